// Round 4
// baseline (407.495 us; speedup 1.0000x reference)
//
#include <hip/hip_runtime.h>
#include <hip/hip_bf16.h>
#include <stdint.h>

// QLSTM: T=256, B=2048, DIN=128, NQ=16, 4 gates. fp32 inputs, fp32 outputs.
// R8: barrier-free per-wave design.
//   - wave = one batch, fully independent: owns ALL 4 W col-block fragments in
//     VGPRs, computes its own 16-t x 64 z-tile with MFMA (same kt/hi-lo ladder
//     order as R7 -> bit-identical z), transposes z through a private per-wave
//     LDS tile (b32 pattern, <=2-way banks). ZERO __syncthreads in the kernel
//     (R7 had 128 barriers x 4-wave lockstep).
//   - gate exchange f/i/g/o via permlane16_swap/permlane32_swap (VALU, ~4cy)
//     + cndmask selects, replacing 4 ds_bpermute (~100cy LDS round-trip) on
//     the serial recurrence chain. __has_builtin-guarded, bpermute fallback.

#define T_STEPS 256
#define BATCH   2048
#define DIN     128
#define NQ      16
#define LCOLS   64
#define DTOT    144
#define NTILE   16          // 16 tiles of 16 timesteps
#define ZROW    68          // padded z row (floats)

typedef __attribute__((ext_vector_type(8))) short bf16x8;
typedef __attribute__((ext_vector_type(4))) float f32x4;
typedef __attribute__((ext_vector_type(2))) int   int2v;

#if defined(__has_builtin)
#if __has_builtin(__builtin_amdgcn_permlane16_swap) && __has_builtin(__builtin_amdgcn_permlane32_swap)
#define USE_PLSWAP 1
#endif
#endif
#ifndef USE_PLSWAP
#define USE_PLSWAP 0
#endif

__device__ __forceinline__ float bf2f(unsigned short u) {
    union { unsigned int i; float f; } v; v.i = ((unsigned int)u) << 16; return v.f;
}
__device__ __forceinline__ unsigned short f2bf(float f) {
    union { float f; unsigned int i; } v; v.f = f;
    unsigned int i = v.i;
    unsigned int r = i + 0x7fffu + ((i >> 16) & 1u);   // round-nearest-even
    return (unsigned short)(r >> 16);
}
__device__ __forceinline__ float ldval(const float* p) { return *p; }
__device__ __forceinline__ float ldval(const unsigned short* p) { return bf2f(*p); }

// ---------------- per-wave dtype detector (bf16=1, fp32=0), wave-uniform ----------------
__device__ __forceinline__ int detect_bf16(const unsigned int* __restrict__ xw, int lane) {
    int cnt = 0;
#pragma unroll
    for (int i = 0; i < 4; ++i) {
        unsigned int w = xw[lane + i * 64];
        unsigned int e = (w >> 7) & 0xFFu;
        cnt += (e >= 100u && e <= 140u) ? 1 : 0;
    }
#pragma unroll
    for (int d = 32; d > 0; d >>= 1) cnt += __shfl_down(cnt, d, 64);
    int tot = __shfl(cnt, 0, 64);
    return (tot >= 140) ? 1 : 0;
}

// ---------------- DPP helpers ----------------
template <int CTRL>
__device__ __forceinline__ float dpp_sh(float v) {   // shift w/ multiplicative identity
    int r = __builtin_amdgcn_update_dpp(__builtin_bit_cast(int, 1.0f),
                                        __builtin_bit_cast(int, v),
                                        CTRL, 0xF, 0xF, false);
    return __builtin_bit_cast(float, r);
}
template <int CTRL>
__device__ __forceinline__ float rot16(float v) {    // row rotate (pure VALU)
    int r = __builtin_amdgcn_update_dpp(0, __builtin_bit_cast(int, v),
                                        CTRL, 0xF, 0xF, false);
    return __builtin_bit_cast(float, r);
}

// ---------------- one recurrence step ----------------
template <int BASE>
__device__ __forceinline__ void qstep(int t, int g, int n, float cur,
                                      const float (&Wp)[16], float& h, float& c,
                                      float& hsave, float* __restrict__ out, int b,
                                      bool m0, bool m1,
                                      int a_f, int a_i, int a_g, int a_o)
{
    float h1  = rot16<0x121>(h), h2  = rot16<0x122>(h), h3  = rot16<0x123>(h);
    float h4  = rot16<0x124>(h), h5  = rot16<0x125>(h), h6  = rot16<0x126>(h), h7  = rot16<0x127>(h);
    float h8  = rot16<0x128>(h), h9  = rot16<0x129>(h), h10 = rot16<0x12A>(h), h11 = rot16<0x12B>(h);
    float h12 = rot16<0x12C>(h), h13 = rot16<0x12D>(h), h14 = rot16<0x12E>(h), h15 = rot16<0x12F>(h);

    float s0 = fmaf(Wp[0],  h,   fmaf(Wp[1],  h1,  fmaf(Wp[2],  h2,  Wp[3]  * h3)));
    float s1 = fmaf(Wp[4],  h4,  fmaf(Wp[5],  h5,  fmaf(Wp[6],  h6,  Wp[7]  * h7)));
    float s2 = fmaf(Wp[8],  h8,  fmaf(Wp[9],  h9,  fmaf(Wp[10], h10, Wp[11] * h11)));
    float s3 = fmaf(Wp[12], h12, fmaf(Wp[13], h13, fmaf(Wp[14], h14, Wp[15] * h15)));
    float z = cur + ((s0 + s1) + (s2 + s3));

    float cz = __cosf(z);
    cz *= dpp_sh<BASE + 1>(cz);
    cz *= dpp_sh<BASE + 2>(cz);
    cz *= dpp_sh<BASE + 4>(cz);
    cz *= dpp_sh<BASE + 8>(cz);

    float a = (g == 2) ? 2.f * cz : cz;
    float e = __expf(-a);
    float rr = __builtin_amdgcn_rcpf(1.f + e);
    float s = (g == 2) ? (1.f - e) * rr : rr;

    float fv, iv, gv, ov;
#if USE_PLSWAP
    // rows r0..r3 = 16-lane gate groups. slot ck holds (at a lane in row g) the
    // value of s from row g^k.  pl16_swap(A,B): A.rows{1,3} <-> B.rows{0,2};
    // pl32_swap(A,B): A.rows{2,3} <-> B.rows{0,1}.
    int si = __builtin_bit_cast(int, s);
    int2v e1 = __builtin_amdgcn_permlane16_swap(si, si, false, false);
    int c1i = m0 ? e1[0] : e1[1];                       // row g^1
    int2v e2 = __builtin_amdgcn_permlane32_swap(si, si, false, false);
    int c2i = m1 ? e2[0] : e2[1];                       // row g^2
    int2v e3 = __builtin_amdgcn_permlane16_swap(c2i, c2i, false, false);
    int c3i = m0 ? e3[0] : e3[1];                       // row g^3
    float C0 = s;
    float C1 = __builtin_bit_cast(float, c1i);
    float C2 = __builtin_bit_cast(float, c2i);
    float C3 = __builtin_bit_cast(float, c3i);
    // row r's value lives in slot g^r:  fv=row0=C[g], iv=row1=C[g^1], ...
    float P  = m1 ? C2 : C0;
    float Q  = m1 ? C3 : C1;
    float R_ = m1 ? C0 : C2;
    float S_ = m1 ? C1 : C3;
    fv = m0 ? Q  : P;
    iv = m0 ? P  : Q;
    gv = m0 ? S_ : R_;
    ov = m0 ? R_ : S_;
#else
    int si = __builtin_bit_cast(int, s);
    fv = __builtin_bit_cast(float, __builtin_amdgcn_ds_bpermute(a_f, si));
    iv = __builtin_bit_cast(float, __builtin_amdgcn_ds_bpermute(a_i, si));
    gv = __builtin_bit_cast(float, __builtin_amdgcn_ds_bpermute(a_g, si));
    ov = __builtin_bit_cast(float, __builtin_amdgcn_ds_bpermute(a_o, si));
#endif

    c = fmaf(fv, c, iv * gv);
    float e2t = __expf(-2.f * c);
    float tc = (1.f - e2t) * __builtin_amdgcn_rcpf(1.f + e2t);
    h = ov * tc;

    if ((t & 3) == g) hsave = h;
    if ((t & 3) == 3)
        out[(size_t)(t - 3 + g) * (BATCH * NQ) + (size_t)b * NQ + n] = hsave;
}

// ---------------- fused per-wave main (no barriers) ----------------
template <int BASE, typename InT>
__device__ __forceinline__ void fused_main(
    const InT* __restrict__ x, const InT* __restrict__ W,
    const InT* __restrict__ bv, const InT* __restrict__ th,
    float* __restrict__ out, int b, int lane,
    const float (&Wp)[16], float (*zt)[16][ZROW])
{
    const int m = lane & 15, quad = lane >> 4;
    const int g = quad, n = m;
    const bool m0 = (g & 1) != 0, m1 = (g & 2) != 0;
    const int a_f = n << 2, a_i = (16 + n) << 2, a_g = (32 + n) << 2, a_o = (48 + n) << 2;

    // W fragments: ALL 4 col-blocks (wave is self-sufficient); hi/lo for fp32
    bf16x8 bh[4][4], bl[4][4];
    if constexpr (sizeof(InT) == 2) {
#pragma unroll
        for (int kt = 0; kt < 4; ++kt)
#pragma unroll
            for (int nb = 0; nb < 4; ++nb)
                bh[kt][nb] = *(const bf16x8*)((const unsigned short*)W +
                             (size_t)(nb * 16 + m) * DTOT + kt * 32 + quad * 8);
    } else {
#pragma unroll
        for (int kt = 0; kt < 4; ++kt)
#pragma unroll
            for (int nb = 0; nb < 4; ++nb) {
                const float* p = (const float*)W + (size_t)(nb * 16 + m) * DTOT + kt * 32 + quad * 8;
#pragma unroll
                for (int j = 0; j < 8; ++j) {
                    float wv = p[j];
                    unsigned short hh = f2bf(wv);
                    bh[kt][nb][j] = (short)hh;
                    bl[kt][nb][j] = (short)f2bf(wv - bf2f(hh));
                }
            }
    }
    const float bias = ldval(bv + lane) + ldval(th + lane);

    // A-rows for tile tl: timesteps tl*16 + m of batch b.
    const InT* xbase = x + ((size_t)m * BATCH + (size_t)b) * DIN + quad * 8;

    f32x4 rx[8]; bf16x8 rbx[4];
    auto LOAD = [&](int tl) {
        const InT* p = xbase + (size_t)tl * ((size_t)16 * BATCH * DIN);
#pragma unroll
        for (int kt = 0; kt < 4; ++kt) {
            if constexpr (sizeof(InT) == 2) {
                rbx[kt] = *(const bf16x8*)(p + kt * 32);
            } else {
                rx[2 * kt]     = *(const f32x4*)((const float*)p + kt * 32);
                rx[2 * kt + 1] = *(const f32x4*)((const float*)p + kt * 32 + 4);
            }
        }
    };
    auto PRODUCE = [&](int tl) {
        f32x4 acc[4] = {};
#pragma unroll
        for (int kt = 0; kt < 4; ++kt) {
            if constexpr (sizeof(InT) == 2) {
#pragma unroll
                for (int nb = 0; nb < 4; ++nb)
                    acc[nb] = __builtin_amdgcn_mfma_f32_16x16x32_bf16(rbx[kt], bh[kt][nb], acc[nb], 0, 0, 0);
            } else {
                bf16x8 ah, al;
#pragma unroll
                for (int j = 0; j < 8; ++j) {
                    float xv = rx[2 * kt + (j >> 2)][j & 3];
                    unsigned short hh = f2bf(xv);
                    ah[j] = (short)hh;
                    al[j] = (short)f2bf(xv - bf2f(hh));
                }
#pragma unroll
                for (int nb = 0; nb < 4; ++nb)
                    acc[nb] = __builtin_amdgcn_mfma_f32_16x16x32_bf16(ah, bh[kt][nb], acc[nb], 0, 0, 0);
#pragma unroll
                for (int nb = 0; nb < 4; ++nb)
                    acc[nb] = __builtin_amdgcn_mfma_f32_16x16x32_bf16(al, bh[kt][nb], acc[nb], 0, 0, 0);
#pragma unroll
                for (int nb = 0; nb < 4; ++nb)
                    acc[nb] = __builtin_amdgcn_mfma_f32_16x16x32_bf16(ah, bl[kt][nb], acc[nb], 0, 0, 0);
            }
        }
        const int buf = tl & 1;
        // z[t = quad*4+r][col = nb*16+m]; banks (16q + 4r + 16nb + m) % 32 -> 2-way = free
#pragma unroll
        for (int nb = 0; nb < 4; ++nb)
#pragma unroll
            for (int r = 0; r < 4; ++r)
                zt[buf][quad * 4 + r][nb * 16 + m] = acc[nb][r];
    };

    float h = 0.f, c = 0.f, hsave = 0.f;

    LOAD(0);
    PRODUCE(0);
    LOAD(1);

#pragma unroll 1
    for (int tl = 0; tl < NTILE; ++tl) {
        const int buf = tl & 1;
        const int t0 = tl * 16;
        float zr0[8], zr1[8];
#pragma unroll
        for (int j = 0; j < 8; ++j) zr0[j] = zt[buf][j][lane] + bias;
        if (tl < NTILE - 1) PRODUCE(tl + 1);
        if (tl < NTILE - 2) LOAD(tl + 2);
#pragma unroll
        for (int j = 0; j < 4; ++j)
            qstep<BASE>(t0 + j, g, n, zr0[j], Wp, h, c, hsave, out, b, m0, m1, a_f, a_i, a_g, a_o);
#pragma unroll
        for (int j = 0; j < 8; ++j) zr1[j] = zt[buf][8 + j][lane] + bias;
#pragma unroll
        for (int j = 4; j < 8; ++j)
            qstep<BASE>(t0 + j, g, n, zr0[j], Wp, h, c, hsave, out, b, m0, m1, a_f, a_i, a_g, a_o);
#pragma unroll
        for (int j = 0; j < 8; ++j)
            qstep<BASE>(t0 + 8 + j, g, n, zr1[j], Wp, h, c, hsave, out, b, m0, m1, a_f, a_i, a_g, a_o);
    }

    if (g == 0) {
        out[(size_t)T_STEPS * BATCH * NQ + (size_t)b * NQ + n] = h;                       // hx
        out[(size_t)T_STEPS * BATCH * NQ + (size_t)BATCH * NQ + (size_t)b * NQ + n] = c;  // cx
    }
}

__global__ __launch_bounds__(256, 2) void qlstm_fused(
    const void* __restrict__ x_, const void* __restrict__ W_,
    const void* __restrict__ b_, const void* __restrict__ th_,
    float* __restrict__ out)
{
    __shared__ float zw[4][2][16][ZROW];   // 34 KiB: per-wave double-buffered z tile

    const int lane = threadIdx.x & 63;
    const int w    = threadIdx.x >> 6;
    const int b    = blockIdx.x * 4 + w;
    const int n    = lane & 15;

    const int isbf = __builtin_amdgcn_readfirstlane(detect_bf16((const unsigned int*)x_, lane));

    // runtime probe of DPP row_ror direction (wave-uniform)
    int pr  = __builtin_amdgcn_update_dpp(0, lane, 0x121, 0xF, 0xF, false);
    int p0r = __shfl(pr, 0, 64);
    const int d = (p0r == 1) ? 1 : 15;

    float Wp[16];
    if (isbf) {
        const unsigned short* W = (const unsigned short*)W_;
#pragma unroll
        for (int k = 0; k < 16; ++k)
            Wp[k] = bf2f(W[(size_t)lane * DTOT + DIN + ((n + k * d) & 15)]);
    } else {
        const float* W = (const float*)W_;
#pragma unroll
        for (int k = 0; k < 16; ++k)
            Wp[k] = W[(size_t)lane * DTOT + DIN + ((n + k * d) & 15)];
    }

    // runtime probe of DPP row_shr direction (wave-uniform) for the prefix product
    int probe = __builtin_amdgcn_update_dpp(999, lane, 0x111, 0xF, 0xF, false);
    int p2 = __shfl(probe, 2, 64);

    if (isbf) {
        if (p2 == 1) fused_main<0x110, unsigned short>((const unsigned short*)x_, (const unsigned short*)W_,
                                                       (const unsigned short*)b_, (const unsigned short*)th_,
                                                       out, b, lane, Wp, zw[w]);
        else         fused_main<0x100, unsigned short>((const unsigned short*)x_, (const unsigned short*)W_,
                                                       (const unsigned short*)b_, (const unsigned short*)th_,
                                                       out, b, lane, Wp, zw[w]);
    } else {
        if (p2 == 1) fused_main<0x110, float>((const float*)x_, (const float*)W_,
                                              (const float*)b_, (const float*)th_,
                                              out, b, lane, Wp, zw[w]);
        else         fused_main<0x100, float>((const float*)x_, (const float*)W_,
                                              (const float*)b_, (const float*)th_,
                                              out, b, lane, Wp, zw[w]);
    }
}

extern "C" void kernel_launch(void* const* d_in, const int* in_sizes, int n_in,
                              void* d_out, int out_size, void* d_ws, size_t ws_size,
                              hipStream_t stream) {
    const void* x  = d_in[0];
    const void* W  = d_in[1];
    const void* bv = d_in[2];
    const void* th = d_in[3];
    (void)d_ws; (void)ws_size;
    qlstm_fused<<<BATCH / 4, 256, 0, stream>>>(x, W, bv, th, (float*)d_out);
}

// Round 5
// 401.427 us; speedup vs baseline: 1.0151x; 1.0151x over previous
//
#include <hip/hip_runtime.h>
#include <hip/hip_bf16.h>
#include <stdint.h>

// QLSTM: T=256, B=2048, DIN=128, NQ=16, 4 gates. fp32 inputs, fp32 outputs.
// R9: R8 barrier-free per-wave design, minus the register spill.
//   - R8 regression diagnosed: all-W-fragments-in-VGPR needs ~220 regs, compiler
//     capped at 128 -> scratch spills (WRITE +13MB, FETCH +6.5MB). Fix: W
//     fragments live in block-shared LDS (wfh/wfl[16][64], built cooperatively
//     once, ONE barrier, read-only after; contiguous lane layout = conflict-free).
//   - z tile single-buffered (16 z rows read into regs before PRODUCE overwrites;
//     same-wave DS ordering, no barrier), ZROW=66 -> store banks {0,8,16,24}+m,
//     fully conflict-free.
//   - gate exchange via permlane16/32_swap (VALU) as R8; MFMA ladder order
//     unchanged -> bit-identical z.

#define T_STEPS 256
#define BATCH   2048
#define DIN     128
#define NQ      16
#define DTOT    144
#define NTILE   16          // 16 tiles of 16 timesteps
#define ZROW    66          // padded z row (floats): 4*ZROW%32=8 -> conflict-free

typedef __attribute__((ext_vector_type(8))) short bf16x8;
typedef __attribute__((ext_vector_type(4))) float f32x4;
typedef __attribute__((ext_vector_type(2))) int   int2v;

#if defined(__has_builtin)
#if __has_builtin(__builtin_amdgcn_permlane16_swap) && __has_builtin(__builtin_amdgcn_permlane32_swap)
#define USE_PLSWAP 1
#endif
#endif
#ifndef USE_PLSWAP
#define USE_PLSWAP 0
#endif

__device__ __forceinline__ float bf2f(unsigned short u) {
    union { unsigned int i; float f; } v; v.i = ((unsigned int)u) << 16; return v.f;
}
__device__ __forceinline__ unsigned short f2bf(float f) {
    union { float f; unsigned int i; } v; v.f = f;
    unsigned int i = v.i;
    unsigned int r = i + 0x7fffu + ((i >> 16) & 1u);   // round-nearest-even
    return (unsigned short)(r >> 16);
}
__device__ __forceinline__ float ldval(const float* p) { return *p; }
__device__ __forceinline__ float ldval(const unsigned short* p) { return bf2f(*p); }

// ---------------- per-wave dtype detector (bf16=1, fp32=0), wave-uniform ----------------
__device__ __forceinline__ int detect_bf16(const unsigned int* __restrict__ xw, int lane) {
    int cnt = 0;
#pragma unroll
    for (int i = 0; i < 4; ++i) {
        unsigned int w = xw[lane + i * 64];
        unsigned int e = (w >> 7) & 0xFFu;
        cnt += (e >= 100u && e <= 140u) ? 1 : 0;
    }
#pragma unroll
    for (int d = 32; d > 0; d >>= 1) cnt += __shfl_down(cnt, d, 64);
    int tot = __shfl(cnt, 0, 64);
    return (tot >= 140) ? 1 : 0;
}

// ---------------- DPP helpers ----------------
template <int CTRL>
__device__ __forceinline__ float dpp_sh(float v) {   // shift w/ multiplicative identity
    int r = __builtin_amdgcn_update_dpp(__builtin_bit_cast(int, 1.0f),
                                        __builtin_bit_cast(int, v),
                                        CTRL, 0xF, 0xF, false);
    return __builtin_bit_cast(float, r);
}
template <int CTRL>
__device__ __forceinline__ float rot16(float v) {    // row rotate (pure VALU)
    int r = __builtin_amdgcn_update_dpp(0, __builtin_bit_cast(int, v),
                                        CTRL, 0xF, 0xF, false);
    return __builtin_bit_cast(float, r);
}

// ---------------- one recurrence step ----------------
template <int BASE>
__device__ __forceinline__ void qstep(int t, int g, int n, float cur,
                                      const float (&Wp)[16], float& h, float& c,
                                      float& hsave, float* __restrict__ out, int b,
                                      bool m0, bool m1,
                                      int a_f, int a_i, int a_g, int a_o)
{
    float h1  = rot16<0x121>(h), h2  = rot16<0x122>(h), h3  = rot16<0x123>(h);
    float h4  = rot16<0x124>(h), h5  = rot16<0x125>(h), h6  = rot16<0x126>(h), h7  = rot16<0x127>(h);
    float h8  = rot16<0x128>(h), h9  = rot16<0x129>(h), h10 = rot16<0x12A>(h), h11 = rot16<0x12B>(h);
    float h12 = rot16<0x12C>(h), h13 = rot16<0x12D>(h), h14 = rot16<0x12E>(h), h15 = rot16<0x12F>(h);

    float s0 = fmaf(Wp[0],  h,   fmaf(Wp[1],  h1,  fmaf(Wp[2],  h2,  Wp[3]  * h3)));
    float s1 = fmaf(Wp[4],  h4,  fmaf(Wp[5],  h5,  fmaf(Wp[6],  h6,  Wp[7]  * h7)));
    float s2 = fmaf(Wp[8],  h8,  fmaf(Wp[9],  h9,  fmaf(Wp[10], h10, Wp[11] * h11)));
    float s3 = fmaf(Wp[12], h12, fmaf(Wp[13], h13, fmaf(Wp[14], h14, Wp[15] * h15)));
    float z = cur + ((s0 + s1) + (s2 + s3));

    float cz = __cosf(z);
    cz *= dpp_sh<BASE + 1>(cz);
    cz *= dpp_sh<BASE + 2>(cz);
    cz *= dpp_sh<BASE + 4>(cz);
    cz *= dpp_sh<BASE + 8>(cz);

    float a = (g == 2) ? 2.f * cz : cz;
    float e = __expf(-a);
    float rr = __builtin_amdgcn_rcpf(1.f + e);
    float s = (g == 2) ? (1.f - e) * rr : rr;

    float fv, iv, gv, ov;
#if USE_PLSWAP
    int si = __builtin_bit_cast(int, s);
    int2v e1 = __builtin_amdgcn_permlane16_swap(si, si, false, false);
    int c1i = m0 ? e1[0] : e1[1];                       // row g^1
    int2v e2 = __builtin_amdgcn_permlane32_swap(si, si, false, false);
    int c2i = m1 ? e2[0] : e2[1];                       // row g^2
    int2v e3 = __builtin_amdgcn_permlane16_swap(c2i, c2i, false, false);
    int c3i = m0 ? e3[0] : e3[1];                       // row g^3
    float C0 = s;
    float C1 = __builtin_bit_cast(float, c1i);
    float C2 = __builtin_bit_cast(float, c2i);
    float C3 = __builtin_bit_cast(float, c3i);
    float P  = m1 ? C2 : C0;
    float Q  = m1 ? C3 : C1;
    float R_ = m1 ? C0 : C2;
    float S_ = m1 ? C1 : C3;
    fv = m0 ? Q  : P;
    iv = m0 ? P  : Q;
    gv = m0 ? S_ : R_;
    ov = m0 ? R_ : S_;
#else
    int si = __builtin_bit_cast(int, s);
    fv = __builtin_bit_cast(float, __builtin_amdgcn_ds_bpermute(a_f, si));
    iv = __builtin_bit_cast(float, __builtin_amdgcn_ds_bpermute(a_i, si));
    gv = __builtin_bit_cast(float, __builtin_amdgcn_ds_bpermute(a_g, si));
    ov = __builtin_bit_cast(float, __builtin_amdgcn_ds_bpermute(a_o, si));
#endif

    c = fmaf(fv, c, iv * gv);
    float e2t = __expf(-2.f * c);
    float tc = (1.f - e2t) * __builtin_amdgcn_rcpf(1.f + e2t);
    h = ov * tc;

    if ((t & 3) == g) hsave = h;
    if ((t & 3) == 3)
        out[(size_t)(t - 3 + g) * (BATCH * NQ) + (size_t)b * NQ + n] = hsave;
}

// ---------------- fused per-wave main ----------------
// wfh/wfl[kt*4+nb][lane]: W MFMA fragments, block-shared, built once.
// zt[16][ZROW]: per-wave private z tile (single buffer).
template <int BASE, typename InT>
__device__ __forceinline__ void fused_main(
    const InT* __restrict__ x, const InT* __restrict__ W,
    const InT* __restrict__ bv, const InT* __restrict__ th,
    float* __restrict__ out, int b, int w, int lane,
    const float (&Wp)[16], float (*zt)[ZROW],
    bf16x8 (*wfh)[64], bf16x8 (*wfl)[64])
{
    const int m = lane & 15, quad = lane >> 4;
    const int g = quad, n = m;
    const bool m0 = (g & 1) != 0, m1 = (g & 2) != 0;
    const int a_f = n << 2, a_i = (16 + n) << 2, a_g = (32 + n) << 2, a_o = (48 + n) << 2;

    // ---- cooperative W-fragment build: wave w handles k-tile kt = w ----
    if constexpr (sizeof(InT) == 2) {
#pragma unroll
        for (int nb = 0; nb < 4; ++nb)
            wfh[w * 4 + nb][lane] = *(const bf16x8*)((const unsigned short*)W +
                                    (size_t)(nb * 16 + m) * DTOT + w * 32 + quad * 8);
    } else {
#pragma unroll
        for (int nb = 0; nb < 4; ++nb) {
            const float* p = (const float*)W + (size_t)(nb * 16 + m) * DTOT + w * 32 + quad * 8;
            bf16x8 ah, al;
#pragma unroll
            for (int j = 0; j < 8; ++j) {
                float wv = p[j];
                unsigned short hh = f2bf(wv);
                ah[j] = (short)hh;
                al[j] = (short)f2bf(wv - bf2f(hh));
            }
            wfh[w * 4 + nb][lane] = ah;
            wfl[w * 4 + nb][lane] = al;
        }
    }
    const float bias = ldval(bv + lane) + ldval(th + lane);
    __syncthreads();            // the ONLY barrier; wf* read-only afterwards

    // A-rows for tile tl: timesteps tl*16 + m of batch b.
    const InT* xbase = x + ((size_t)m * BATCH + (size_t)b) * DIN + quad * 8;

    f32x4 rx[8]; bf16x8 rbx[4];
    auto LOAD = [&](int tl) {
        const InT* p = xbase + (size_t)tl * ((size_t)16 * BATCH * DIN);
#pragma unroll
        for (int kt = 0; kt < 4; ++kt) {
            if constexpr (sizeof(InT) == 2) {
                rbx[kt] = *(const bf16x8*)(p + kt * 32);
            } else {
                rx[2 * kt]     = *(const f32x4*)((const float*)p + kt * 32);
                rx[2 * kt + 1] = *(const f32x4*)((const float*)p + kt * 32 + 4);
            }
        }
    };
    auto PRODUCE = [&]() {
        f32x4 acc[4] = {};
#pragma unroll
        for (int kt = 0; kt < 4; ++kt) {
            if constexpr (sizeof(InT) == 2) {
#pragma unroll
                for (int nb = 0; nb < 4; ++nb)
                    acc[nb] = __builtin_amdgcn_mfma_f32_16x16x32_bf16(rbx[kt], wfh[kt * 4 + nb][lane], acc[nb], 0, 0, 0);
            } else {
                bf16x8 ah, al;
#pragma unroll
                for (int j = 0; j < 8; ++j) {
                    float xv = rx[2 * kt + (j >> 2)][j & 3];
                    unsigned short hh = f2bf(xv);
                    ah[j] = (short)hh;
                    al[j] = (short)f2bf(xv - bf2f(hh));
                }
#pragma unroll
                for (int nb = 0; nb < 4; ++nb)
                    acc[nb] = __builtin_amdgcn_mfma_f32_16x16x32_bf16(ah, wfh[kt * 4 + nb][lane], acc[nb], 0, 0, 0);
#pragma unroll
                for (int nb = 0; nb < 4; ++nb)
                    acc[nb] = __builtin_amdgcn_mfma_f32_16x16x32_bf16(al, wfh[kt * 4 + nb][lane], acc[nb], 0, 0, 0);
#pragma unroll
                for (int nb = 0; nb < 4; ++nb)
                    acc[nb] = __builtin_amdgcn_mfma_f32_16x16x32_bf16(ah, wfl[kt * 4 + nb][lane], acc[nb], 0, 0, 0);
            }
        }
        // z[t = quad*4+r][col = nb*16+m]; banks (8*quad + m) % 32 -> conflict-free
#pragma unroll
        for (int nb = 0; nb < 4; ++nb)
#pragma unroll
            for (int r = 0; r < 4; ++r)
                zt[quad * 4 + r][nb * 16 + m] = acc[nb][r];
    };

    float h = 0.f, c = 0.f, hsave = 0.f;

    LOAD(0);
    PRODUCE();
    LOAD(1);

#pragma unroll 1
    for (int tl = 0; tl < NTILE; ++tl) {
        const int t0 = tl * 16;
        float zr[16];
#pragma unroll
        for (int j = 0; j < 16; ++j) zr[j] = zt[j][lane] + bias;   // drain before overwrite
        if (tl < NTILE - 1) PRODUCE();
        if (tl < NTILE - 2) LOAD(tl + 2);
#pragma unroll
        for (int j = 0; j < 16; ++j)
            qstep<BASE>(t0 + j, g, n, zr[j], Wp, h, c, hsave, out, b, m0, m1, a_f, a_i, a_g, a_o);
    }

    if (g == 0) {
        out[(size_t)T_STEPS * BATCH * NQ + (size_t)b * NQ + n] = h;                       // hx
        out[(size_t)T_STEPS * BATCH * NQ + (size_t)BATCH * NQ + (size_t)b * NQ + n] = c;  // cx
    }
}

__global__ __launch_bounds__(256, 2) void qlstm_fused(
    const void* __restrict__ x_, const void* __restrict__ W_,
    const void* __restrict__ b_, const void* __restrict__ th_,
    float* __restrict__ out)
{
    __shared__ float  zw[4][NTILE][ZROW];   // 16.5 KiB: per-wave z tiles
    __shared__ bf16x8 wfh[16][64];          // 16 KiB: W hi fragments (shared)
    __shared__ bf16x8 wfl[16][64];          // 16 KiB: W lo fragments (fp32 path)

    const int lane = threadIdx.x & 63;
    const int w    = threadIdx.x >> 6;
    const int b    = blockIdx.x * 4 + w;
    const int n    = lane & 15;

    const int isbf = __builtin_amdgcn_readfirstlane(detect_bf16((const unsigned int*)x_, lane));

    // runtime probe of DPP row_ror direction (wave-uniform)
    int pr  = __builtin_amdgcn_update_dpp(0, lane, 0x121, 0xF, 0xF, false);
    int p0r = __shfl(pr, 0, 64);
    const int d = (p0r == 1) ? 1 : 15;

    float Wp[16];
    if (isbf) {
        const unsigned short* W = (const unsigned short*)W_;
#pragma unroll
        for (int k = 0; k < 16; ++k)
            Wp[k] = bf2f(W[(size_t)lane * DTOT + DIN + ((n + k * d) & 15)]);
    } else {
        const float* W = (const float*)W_;
#pragma unroll
        for (int k = 0; k < 16; ++k)
            Wp[k] = W[(size_t)lane * DTOT + DIN + ((n + k * d) & 15)];
    }

    // runtime probe of DPP row_shr direction (wave-uniform) for the prefix product
    int probe = __builtin_amdgcn_update_dpp(999, lane, 0x111, 0xF, 0xF, false);
    int p2 = __shfl(probe, 2, 64);

    if (isbf) {
        if (p2 == 1) fused_main<0x110, unsigned short>((const unsigned short*)x_, (const unsigned short*)W_,
                                                       (const unsigned short*)b_, (const unsigned short*)th_,
                                                       out, b, w, lane, Wp, zw[w], wfh, wfl);
        else         fused_main<0x100, unsigned short>((const unsigned short*)x_, (const unsigned short*)W_,
                                                       (const unsigned short*)b_, (const unsigned short*)th_,
                                                       out, b, w, lane, Wp, zw[w], wfh, wfl);
    } else {
        if (p2 == 1) fused_main<0x110, float>((const float*)x_, (const float*)W_,
                                              (const float*)b_, (const float*)th_,
                                              out, b, w, lane, Wp, zw[w], wfh, wfl);
        else         fused_main<0x100, float>((const float*)x_, (const float*)W_,
                                              (const float*)b_, (const float*)th_,
                                              out, b, w, lane, Wp, zw[w], wfh, wfl);
    }
}

extern "C" void kernel_launch(void* const* d_in, const int* in_sizes, int n_in,
                              void* d_out, int out_size, void* d_ws, size_t ws_size,
                              hipStream_t stream) {
    const void* x  = d_in[0];
    const void* W  = d_in[1];
    const void* bv = d_in[2];
    const void* th = d_in[3];
    (void)d_ws; (void)ws_size;
    qlstm_fused<<<BATCH / 4, 256, 0, stream>>>(x, W, bv, th, (float*)d_out);
}

// Round 6
// 388.667 us; speedup vs baseline: 1.0484x; 1.0328x over previous
//
#include <hip/hip_runtime.h>
#include <hip/hip_bf16.h>
#include <stdint.h>

// QLSTM: T=256, B=2048, DIN=128, NQ=16, 4 gates. fp32 inputs, fp32 outputs.
// R10: R9 structure + DPP-fused qstep VALU stream.
//   - h-dot: 16 v_fmac_f32_dpp/v_mul_f32_dpp with row_ror:k (rotate fused into
//     the fma; was 15 mov_dpp + 16 VOP3 fma = 34 inst, now 17 + 3 adds).
//     4 independent accumulator chains interleaved 4-apart (no intra-block
//     VALU->DPP hazards); leading s_nop 1 covers the h-write hazard.
//   - prefix product: 4x in-place v_mul_f32_dpp cz,cz,cz row_shr:k (BC=0
//     preserves dst on invalid lanes = multiplicative identity fill; semantics
//     HW-verified by the old update_dpp(old=1.0) path). s_nop 1 between stages
//     (VALU-write -> DPP-read needs 2 wait states, compiler can't see into asm).
//   - everything else identical to R9 (W frags in LDS, single-buffer z tile,
//     permlane gate exchange, one barrier total).

#define T_STEPS 256
#define BATCH   2048
#define DIN     128
#define NQ      16
#define DTOT    144
#define NTILE   16          // 16 tiles of 16 timesteps
#define ZROW    66          // padded z row (floats): 4*ZROW%32=8 -> conflict-free

typedef __attribute__((ext_vector_type(8))) short bf16x8;
typedef __attribute__((ext_vector_type(4))) float f32x4;
typedef __attribute__((ext_vector_type(2))) int   int2v;

#if defined(__has_builtin)
#if __has_builtin(__builtin_amdgcn_permlane16_swap) && __has_builtin(__builtin_amdgcn_permlane32_swap)
#define USE_PLSWAP 1
#endif
#endif
#ifndef USE_PLSWAP
#define USE_PLSWAP 0
#endif

__device__ __forceinline__ float bf2f(unsigned short u) {
    union { unsigned int i; float f; } v; v.i = ((unsigned int)u) << 16; return v.f;
}
__device__ __forceinline__ unsigned short f2bf(float f) {
    union { float f; unsigned int i; } v; v.f = f;
    unsigned int i = v.i;
    unsigned int r = i + 0x7fffu + ((i >> 16) & 1u);   // round-nearest-even
    return (unsigned short)(r >> 16);
}
__device__ __forceinline__ float ldval(const float* p) { return *p; }
__device__ __forceinline__ float ldval(const unsigned short* p) { return bf2f(*p); }

// ---------------- per-wave dtype detector (bf16=1, fp32=0), wave-uniform ----------------
__device__ __forceinline__ int detect_bf16(const unsigned int* __restrict__ xw, int lane) {
    int cnt = 0;
#pragma unroll
    for (int i = 0; i < 4; ++i) {
        unsigned int w = xw[lane + i * 64];
        unsigned int e = (w >> 7) & 0xFFu;
        cnt += (e >= 100u && e <= 140u) ? 1 : 0;
    }
#pragma unroll
    for (int d = 32; d > 0; d >>= 1) cnt += __shfl_down(cnt, d, 64);
    int tot = __shfl(cnt, 0, 64);
    return (tot >= 140) ? 1 : 0;
}

// ---------------- one recurrence step ----------------
template <int BASE>
__device__ __forceinline__ void qstep(int t, int g, int n, float cur,
                                      const float (&Wp)[16], float& h, float& c,
                                      float& hsave, float* __restrict__ out, int b,
                                      bool m0, bool m1,
                                      int a_f, int a_i, int a_g, int a_o)
{
    // h-dot: rotate fused into fmac via DPP. 4 chains interleaved 4-apart so
    // no accumulator is touched by consecutive instructions; all DPP sources
    // are h (written well before; s_nop 1 guards the 2 wait states anyway).
    float a0 = cur, a1, a2, a3;
    asm volatile(
        "s_nop 1\n\t"
        "v_fmac_f32 %0, %4, %5\n\t"
        "v_mul_f32_dpp %1, %4, %6 row_ror:4 row_mask:0xf bank_mask:0xf\n\t"
        "v_mul_f32_dpp %2, %4, %7 row_ror:8 row_mask:0xf bank_mask:0xf\n\t"
        "v_mul_f32_dpp %3, %4, %8 row_ror:12 row_mask:0xf bank_mask:0xf\n\t"
        "v_fmac_f32_dpp %0, %4, %9 row_ror:1 row_mask:0xf bank_mask:0xf\n\t"
        "v_fmac_f32_dpp %1, %4, %10 row_ror:5 row_mask:0xf bank_mask:0xf\n\t"
        "v_fmac_f32_dpp %2, %4, %11 row_ror:9 row_mask:0xf bank_mask:0xf\n\t"
        "v_fmac_f32_dpp %3, %4, %12 row_ror:13 row_mask:0xf bank_mask:0xf\n\t"
        "v_fmac_f32_dpp %0, %4, %13 row_ror:2 row_mask:0xf bank_mask:0xf\n\t"
        "v_fmac_f32_dpp %1, %4, %14 row_ror:6 row_mask:0xf bank_mask:0xf\n\t"
        "v_fmac_f32_dpp %2, %4, %15 row_ror:10 row_mask:0xf bank_mask:0xf\n\t"
        "v_fmac_f32_dpp %3, %4, %16 row_ror:14 row_mask:0xf bank_mask:0xf\n\t"
        "v_fmac_f32_dpp %0, %4, %17 row_ror:3 row_mask:0xf bank_mask:0xf\n\t"
        "v_fmac_f32_dpp %1, %4, %18 row_ror:7 row_mask:0xf bank_mask:0xf\n\t"
        "v_fmac_f32_dpp %2, %4, %19 row_ror:11 row_mask:0xf bank_mask:0xf\n\t"
        "v_fmac_f32_dpp %3, %4, %20 row_ror:15 row_mask:0xf bank_mask:0xf"
        : "+v"(a0), "=&v"(a1), "=&v"(a2), "=&v"(a3)
        : "v"(h), "v"(Wp[0]), "v"(Wp[4]), "v"(Wp[8]), "v"(Wp[12]),
          "v"(Wp[1]), "v"(Wp[5]), "v"(Wp[9]), "v"(Wp[13]),
          "v"(Wp[2]), "v"(Wp[6]), "v"(Wp[10]), "v"(Wp[14]),
          "v"(Wp[3]), "v"(Wp[7]), "v"(Wp[11]), "v"(Wp[15]));
    float z = (a0 + a1) + (a2 + a3);

    float cz = __cosf(z);
    // inclusive prefix product, in-place DPP Hillis-Steele: invalid lanes keep
    // dst (BC=0) = multiplicative identity. s_nop 1 between dependent stages.
    if constexpr (BASE == 0x110) {
        asm volatile(
            "s_nop 1\n\t"
            "v_mul_f32_dpp %0, %0, %0 row_shr:1 row_mask:0xf bank_mask:0xf\n\t"
            "s_nop 1\n\t"
            "v_mul_f32_dpp %0, %0, %0 row_shr:2 row_mask:0xf bank_mask:0xf\n\t"
            "s_nop 1\n\t"
            "v_mul_f32_dpp %0, %0, %0 row_shr:4 row_mask:0xf bank_mask:0xf\n\t"
            "s_nop 1\n\t"
            "v_mul_f32_dpp %0, %0, %0 row_shr:8 row_mask:0xf bank_mask:0xf"
            : "+v"(cz));
    } else {
        asm volatile(
            "s_nop 1\n\t"
            "v_mul_f32_dpp %0, %0, %0 row_shl:1 row_mask:0xf bank_mask:0xf\n\t"
            "s_nop 1\n\t"
            "v_mul_f32_dpp %0, %0, %0 row_shl:2 row_mask:0xf bank_mask:0xf\n\t"
            "s_nop 1\n\t"
            "v_mul_f32_dpp %0, %0, %0 row_shl:4 row_mask:0xf bank_mask:0xf\n\t"
            "s_nop 1\n\t"
            "v_mul_f32_dpp %0, %0, %0 row_shl:8 row_mask:0xf bank_mask:0xf"
            : "+v"(cz));
    }

    float a = (g == 2) ? 2.f * cz : cz;
    float e = __expf(-a);
    float rr = __builtin_amdgcn_rcpf(1.f + e);
    float s = (g == 2) ? (1.f - e) * rr : rr;

    float fv, iv, gv, ov;
#if USE_PLSWAP
    int si = __builtin_bit_cast(int, s);
    int2v e1 = __builtin_amdgcn_permlane16_swap(si, si, false, false);
    int c1i = m0 ? e1[0] : e1[1];                       // row g^1
    int2v e2 = __builtin_amdgcn_permlane32_swap(si, si, false, false);
    int c2i = m1 ? e2[0] : e2[1];                       // row g^2
    int2v e3 = __builtin_amdgcn_permlane16_swap(c2i, c2i, false, false);
    int c3i = m0 ? e3[0] : e3[1];                       // row g^3
    float C0 = s;
    float C1 = __builtin_bit_cast(float, c1i);
    float C2 = __builtin_bit_cast(float, c2i);
    float C3 = __builtin_bit_cast(float, c3i);
    float P  = m1 ? C2 : C0;
    float Q  = m1 ? C3 : C1;
    float R_ = m1 ? C0 : C2;
    float S_ = m1 ? C1 : C3;
    fv = m0 ? Q  : P;
    iv = m0 ? P  : Q;
    gv = m0 ? S_ : R_;
    ov = m0 ? R_ : S_;
#else
    int si = __builtin_bit_cast(int, s);
    fv = __builtin_bit_cast(float, __builtin_amdgcn_ds_bpermute(a_f, si));
    iv = __builtin_bit_cast(float, __builtin_amdgcn_ds_bpermute(a_i, si));
    gv = __builtin_bit_cast(float, __builtin_amdgcn_ds_bpermute(a_g, si));
    ov = __builtin_bit_cast(float, __builtin_amdgcn_ds_bpermute(a_o, si));
#endif

    c = fmaf(fv, c, iv * gv);
    float e2t = __expf(-2.f * c);
    float tc = (1.f - e2t) * __builtin_amdgcn_rcpf(1.f + e2t);
    h = ov * tc;

    if ((t & 3) == g) hsave = h;
    if ((t & 3) == 3)
        out[(size_t)(t - 3 + g) * (BATCH * NQ) + (size_t)b * NQ + n] = hsave;
}

// ---------------- fused per-wave main ----------------
// wfh/wfl[kt*4+nb][lane]: W MFMA fragments, block-shared, built once.
// zt[16][ZROW]: per-wave private z tile (single buffer).
template <int BASE, typename InT>
__device__ __forceinline__ void fused_main(
    const InT* __restrict__ x, const InT* __restrict__ W,
    const InT* __restrict__ bv, const InT* __restrict__ th,
    float* __restrict__ out, int b, int w, int lane,
    const float (&Wp)[16], float (*zt)[ZROW],
    bf16x8 (*wfh)[64], bf16x8 (*wfl)[64])
{
    const int m = lane & 15, quad = lane >> 4;
    const int g = quad, n = m;
    const bool m0 = (g & 1) != 0, m1 = (g & 2) != 0;
    const int a_f = n << 2, a_i = (16 + n) << 2, a_g = (32 + n) << 2, a_o = (48 + n) << 2;

    // ---- cooperative W-fragment build: wave w handles k-tile kt = w ----
    if constexpr (sizeof(InT) == 2) {
#pragma unroll
        for (int nb = 0; nb < 4; ++nb)
            wfh[w * 4 + nb][lane] = *(const bf16x8*)((const unsigned short*)W +
                                    (size_t)(nb * 16 + m) * DTOT + w * 32 + quad * 8);
    } else {
#pragma unroll
        for (int nb = 0; nb < 4; ++nb) {
            const float* p = (const float*)W + (size_t)(nb * 16 + m) * DTOT + w * 32 + quad * 8;
            bf16x8 ah, al;
#pragma unroll
            for (int j = 0; j < 8; ++j) {
                float wv = p[j];
                unsigned short hh = f2bf(wv);
                ah[j] = (short)hh;
                al[j] = (short)f2bf(wv - bf2f(hh));
            }
            wfh[w * 4 + nb][lane] = ah;
            wfl[w * 4 + nb][lane] = al;
        }
    }
    const float bias = ldval(bv + lane) + ldval(th + lane);
    __syncthreads();            // the ONLY barrier; wf* read-only afterwards

    // A-rows for tile tl: timesteps tl*16 + m of batch b.
    const InT* xbase = x + ((size_t)m * BATCH + (size_t)b) * DIN + quad * 8;

    f32x4 rx[8]; bf16x8 rbx[4];
    auto LOAD = [&](int tl) {
        const InT* p = xbase + (size_t)tl * ((size_t)16 * BATCH * DIN);
#pragma unroll
        for (int kt = 0; kt < 4; ++kt) {
            if constexpr (sizeof(InT) == 2) {
                rbx[kt] = *(const bf16x8*)(p + kt * 32);
            } else {
                rx[2 * kt]     = *(const f32x4*)((const float*)p + kt * 32);
                rx[2 * kt + 1] = *(const f32x4*)((const float*)p + kt * 32 + 4);
            }
        }
    };
    auto PRODUCE = [&]() {
        f32x4 acc[4] = {};
#pragma unroll
        for (int kt = 0; kt < 4; ++kt) {
            if constexpr (sizeof(InT) == 2) {
#pragma unroll
                for (int nb = 0; nb < 4; ++nb)
                    acc[nb] = __builtin_amdgcn_mfma_f32_16x16x32_bf16(rbx[kt], wfh[kt * 4 + nb][lane], acc[nb], 0, 0, 0);
            } else {
                bf16x8 ah, al;
#pragma unroll
                for (int j = 0; j < 8; ++j) {
                    float xv = rx[2 * kt + (j >> 2)][j & 3];
                    unsigned short hh = f2bf(xv);
                    ah[j] = (short)hh;
                    al[j] = (short)f2bf(xv - bf2f(hh));
                }
#pragma unroll
                for (int nb = 0; nb < 4; ++nb)
                    acc[nb] = __builtin_amdgcn_mfma_f32_16x16x32_bf16(ah, wfh[kt * 4 + nb][lane], acc[nb], 0, 0, 0);
#pragma unroll
                for (int nb = 0; nb < 4; ++nb)
                    acc[nb] = __builtin_amdgcn_mfma_f32_16x16x32_bf16(al, wfh[kt * 4 + nb][lane], acc[nb], 0, 0, 0);
#pragma unroll
                for (int nb = 0; nb < 4; ++nb)
                    acc[nb] = __builtin_amdgcn_mfma_f32_16x16x32_bf16(ah, wfl[kt * 4 + nb][lane], acc[nb], 0, 0, 0);
            }
        }
        // z[t = quad*4+r][col = nb*16+m]; banks (8*quad + m) % 32 -> conflict-free
#pragma unroll
        for (int nb = 0; nb < 4; ++nb)
#pragma unroll
            for (int r = 0; r < 4; ++r)
                zt[quad * 4 + r][nb * 16 + m] = acc[nb][r];
    };

    float h = 0.f, c = 0.f, hsave = 0.f;

    LOAD(0);
    PRODUCE();
    LOAD(1);

#pragma unroll 1
    for (int tl = 0; tl < NTILE; ++tl) {
        const int t0 = tl * 16;
        float zr[16];
#pragma unroll
        for (int j = 0; j < 16; ++j) zr[j] = zt[j][lane] + bias;   // drain before overwrite
        if (tl < NTILE - 1) PRODUCE();
        if (tl < NTILE - 2) LOAD(tl + 2);
#pragma unroll
        for (int j = 0; j < 16; ++j)
            qstep<BASE>(t0 + j, g, n, zr[j], Wp, h, c, hsave, out, b, m0, m1, a_f, a_i, a_g, a_o);
    }

    if (g == 0) {
        out[(size_t)T_STEPS * BATCH * NQ + (size_t)b * NQ + n] = h;                       // hx
        out[(size_t)T_STEPS * BATCH * NQ + (size_t)BATCH * NQ + (size_t)b * NQ + n] = c;  // cx
    }
}

__global__ __launch_bounds__(256, 2) void qlstm_fused(
    const void* __restrict__ x_, const void* __restrict__ W_,
    const void* __restrict__ b_, const void* __restrict__ th_,
    float* __restrict__ out)
{
    __shared__ float  zw[4][NTILE][ZROW];   // 16.5 KiB: per-wave z tiles
    __shared__ bf16x8 wfh[16][64];          // 16 KiB: W hi fragments (shared)
    __shared__ bf16x8 wfl[16][64];          // 16 KiB: W lo fragments (fp32 path)

    const int lane = threadIdx.x & 63;
    const int w    = threadIdx.x >> 6;
    const int b    = blockIdx.x * 4 + w;
    const int n    = lane & 15;

    const int isbf = __builtin_amdgcn_readfirstlane(detect_bf16((const unsigned int*)x_, lane));

    // runtime probe of DPP row_ror direction (wave-uniform)
    int pr  = __builtin_amdgcn_update_dpp(0, lane, 0x121, 0xF, 0xF, false);
    int p0r = __shfl(pr, 0, 64);
    const int d = (p0r == 1) ? 1 : 15;

    float Wp[16];
    if (isbf) {
        const unsigned short* W = (const unsigned short*)W_;
#pragma unroll
        for (int k = 0; k < 16; ++k)
            Wp[k] = bf2f(W[(size_t)lane * DTOT + DIN + ((n + k * d) & 15)]);
    } else {
        const float* W = (const float*)W_;
#pragma unroll
        for (int k = 0; k < 16; ++k)
            Wp[k] = W[(size_t)lane * DTOT + DIN + ((n + k * d) & 15)];
    }

    // runtime probe of DPP row_shr direction (wave-uniform) for the prefix product
    int probe = __builtin_amdgcn_update_dpp(999, lane, 0x111, 0xF, 0xF, false);
    int p2 = __shfl(probe, 2, 64);

    if (isbf) {
        if (p2 == 1) fused_main<0x110, unsigned short>((const unsigned short*)x_, (const unsigned short*)W_,
                                                       (const unsigned short*)b_, (const unsigned short*)th_,
                                                       out, b, w, lane, Wp, zw[w], wfh, wfl);
        else         fused_main<0x100, unsigned short>((const unsigned short*)x_, (const unsigned short*)W_,
                                                       (const unsigned short*)b_, (const unsigned short*)th_,
                                                       out, b, w, lane, Wp, zw[w], wfh, wfl);
    } else {
        if (p2 == 1) fused_main<0x110, float>((const float*)x_, (const float*)W_,
                                              (const float*)b_, (const float*)th_,
                                              out, b, w, lane, Wp, zw[w], wfh, wfl);
        else         fused_main<0x100, float>((const float*)x_, (const float*)W_,
                                              (const float*)b_, (const float*)th_,
                                              out, b, w, lane, Wp, zw[w], wfh, wfl);
    }
}

extern "C" void kernel_launch(void* const* d_in, const int* in_sizes, int n_in,
                              void* d_out, int out_size, void* d_ws, size_t ws_size,
                              hipStream_t stream) {
    const void* x  = d_in[0];
    const void* W  = d_in[1];
    const void* bv = d_in[2];
    const void* th = d_in[3];
    (void)d_ws; (void)ws_size;
    qlstm_fused<<<BATCH / 4, 256, 0, stream>>>(x, W, bv, th, (float*)d_out);
}

// Round 7
// 385.052 us; speedup vs baseline: 1.0583x; 1.0094x over previous
//
#include <hip/hip_runtime.h>
#include <hip/hip_bf16.h>
#include <stdint.h>

// QLSTM: T=256, B=2048, DIN=128, NQ=16, 4 gates. fp32 inputs, fp32 outputs.
// R11: two interleaved batches per wave (ILP replaces missing TLP).
//   - R10 diagnosis: occupancy grid-capped at 2 waves/SIMD (2048 waves / 1024
//     SIMDs); single serial chain per wave leaves ~43% issue idle on dependent
//     latency. Fix: 1024 waves, each running TWO independent recurrence chains
//     (batches 2k, 2k+1) interleaved instruction-by-instruction.
//   - combined dot asm: 32 A/B-alternating v_fmac_f32_dpp, reuse distance 8 -> no nops.
//   - combined prefix asm: 8 alternating DPP muls, hazard gaps filled by the
//     other chain -> no nops.
//   - MFMA tile: A-rows = 8 timesteps x 2 batches (row m <-> batch m>>3, t m&7),
//     same kt/hi-lo ladder per output element -> bit-identical z. 32 tiles.
//   - per-lane-const folded gates: s = fmaf(ksc, rcp(1+exp2(cz*kexp)), koff);
//     tanh(c) = fmaf(2, rcp(1+exp2(-2.885*c)), -1)  (same values, fewer inst).
//   - W frags in LDS (R9), zt[16][ZROW] per wave, one barrier total.

#define T_STEPS 256
#define BATCH   2048
#define DIN     128
#define NQ      16
#define DTOT    144
#define NTILE   32          // 32 tiles of 8 timesteps
#define ZROW    66          // padded z row (floats)

typedef __attribute__((ext_vector_type(8))) short bf16x8;
typedef __attribute__((ext_vector_type(4))) float f32x4;
typedef __attribute__((ext_vector_type(2))) int   int2v;

#if defined(__has_builtin)
#if __has_builtin(__builtin_amdgcn_permlane16_swap) && __has_builtin(__builtin_amdgcn_permlane32_swap)
#define USE_PLSWAP 1
#endif
#endif
#ifndef USE_PLSWAP
#define USE_PLSWAP 0
#endif

__device__ __forceinline__ float bf2f(unsigned short u) {
    union { unsigned int i; float f; } v; v.i = ((unsigned int)u) << 16; return v.f;
}
__device__ __forceinline__ unsigned short f2bf(float f) {
    union { float f; unsigned int i; } v; v.f = f;
    unsigned int i = v.i;
    unsigned int r = i + 0x7fffu + ((i >> 16) & 1u);   // round-nearest-even
    return (unsigned short)(r >> 16);
}
__device__ __forceinline__ float ldval(const float* p) { return *p; }
__device__ __forceinline__ float ldval(const unsigned short* p) { return bf2f(*p); }

// ---------------- per-wave dtype detector (bf16=1, fp32=0), wave-uniform ----------------
__device__ __forceinline__ int detect_bf16(const unsigned int* __restrict__ xw, int lane) {
    int cnt = 0;
#pragma unroll
    for (int i = 0; i < 4; ++i) {
        unsigned int w = xw[lane + i * 64];
        unsigned int e = (w >> 7) & 0xFFu;
        cnt += (e >= 100u && e <= 140u) ? 1 : 0;
    }
#pragma unroll
    for (int d = 32; d > 0; d >>= 1) cnt += __shfl_down(cnt, d, 64);
    int tot = __shfl(cnt, 0, 64);
    return (tot >= 140) ? 1 : 0;
}

// ---------------- gate exchange: s(row g) -> f/i/g/o at qubit n ----------------
__device__ __forceinline__ void gex(float s, bool m0, bool m1,
                                    int a_f, int a_i, int a_g, int a_o,
                                    float& fv, float& iv, float& gv, float& ov)
{
#if USE_PLSWAP
    int si = __builtin_bit_cast(int, s);
    int2v e1 = __builtin_amdgcn_permlane16_swap(si, si, false, false);
    int c1i = m0 ? e1[0] : e1[1];                       // row g^1
    int2v e2 = __builtin_amdgcn_permlane32_swap(si, si, false, false);
    int c2i = m1 ? e2[0] : e2[1];                       // row g^2
    int2v e3 = __builtin_amdgcn_permlane16_swap(c2i, c2i, false, false);
    int c3i = m0 ? e3[0] : e3[1];                       // row g^3
    float C0 = s;
    float C1 = __builtin_bit_cast(float, c1i);
    float C2 = __builtin_bit_cast(float, c2i);
    float C3 = __builtin_bit_cast(float, c3i);
    float P  = m1 ? C2 : C0;
    float Q  = m1 ? C3 : C1;
    float R_ = m1 ? C0 : C2;
    float S_ = m1 ? C1 : C3;
    fv = m0 ? Q  : P;
    iv = m0 ? P  : Q;
    gv = m0 ? S_ : R_;
    ov = m0 ? R_ : S_;
#else
    int si = __builtin_bit_cast(int, s);
    fv = __builtin_bit_cast(float, __builtin_amdgcn_ds_bpermute(a_f, si));
    iv = __builtin_bit_cast(float, __builtin_amdgcn_ds_bpermute(a_i, si));
    gv = __builtin_bit_cast(float, __builtin_amdgcn_ds_bpermute(a_g, si));
    ov = __builtin_bit_cast(float, __builtin_amdgcn_ds_bpermute(a_o, si));
#endif
}

// ---------------- one recurrence step for TWO batches ----------------
template <int BASE>
__device__ __forceinline__ void qstep2(int t, int g, int n,
                                       float curA, float curB, const float (&Wp)[16],
                                       float& hA, float& cA, float& hsA, int bA,
                                       float& hB, float& cB, float& hsB, int bB,
                                       bool m0, bool m1,
                                       float kexp, float ksc, float koff,
                                       int a_f, int a_i, int a_g, int a_o,
                                       float* __restrict__ out)
{
    // combined h-dot: A/B chains interleaved; accumulator reuse distance 8 inst.
    float a0A = curA, a1A, a2A, a3A;
    float a0B = curB, a1B, a2B, a3B;
    asm volatile(
        "s_nop 1\n\t"
        "v_fmac_f32 %0, %8, %10\n\t"
        "v_fmac_f32 %4, %9, %10\n\t"
        "v_mul_f32_dpp %1, %8, %11 row_ror:4 row_mask:0xf bank_mask:0xf\n\t"
        "v_mul_f32_dpp %5, %9, %11 row_ror:4 row_mask:0xf bank_mask:0xf\n\t"
        "v_mul_f32_dpp %2, %8, %12 row_ror:8 row_mask:0xf bank_mask:0xf\n\t"
        "v_mul_f32_dpp %6, %9, %12 row_ror:8 row_mask:0xf bank_mask:0xf\n\t"
        "v_mul_f32_dpp %3, %8, %13 row_ror:12 row_mask:0xf bank_mask:0xf\n\t"
        "v_mul_f32_dpp %7, %9, %13 row_ror:12 row_mask:0xf bank_mask:0xf\n\t"
        "v_fmac_f32_dpp %0, %8, %14 row_ror:1 row_mask:0xf bank_mask:0xf\n\t"
        "v_fmac_f32_dpp %4, %9, %14 row_ror:1 row_mask:0xf bank_mask:0xf\n\t"
        "v_fmac_f32_dpp %1, %8, %15 row_ror:5 row_mask:0xf bank_mask:0xf\n\t"
        "v_fmac_f32_dpp %5, %9, %15 row_ror:5 row_mask:0xf bank_mask:0xf\n\t"
        "v_fmac_f32_dpp %2, %8, %16 row_ror:9 row_mask:0xf bank_mask:0xf\n\t"
        "v_fmac_f32_dpp %6, %9, %16 row_ror:9 row_mask:0xf bank_mask:0xf\n\t"
        "v_fmac_f32_dpp %3, %8, %17 row_ror:13 row_mask:0xf bank_mask:0xf\n\t"
        "v_fmac_f32_dpp %7, %9, %17 row_ror:13 row_mask:0xf bank_mask:0xf\n\t"
        "v_fmac_f32_dpp %0, %8, %18 row_ror:2 row_mask:0xf bank_mask:0xf\n\t"
        "v_fmac_f32_dpp %4, %9, %18 row_ror:2 row_mask:0xf bank_mask:0xf\n\t"
        "v_fmac_f32_dpp %1, %8, %19 row_ror:6 row_mask:0xf bank_mask:0xf\n\t"
        "v_fmac_f32_dpp %5, %9, %19 row_ror:6 row_mask:0xf bank_mask:0xf\n\t"
        "v_fmac_f32_dpp %2, %8, %20 row_ror:10 row_mask:0xf bank_mask:0xf\n\t"
        "v_fmac_f32_dpp %6, %9, %20 row_ror:10 row_mask:0xf bank_mask:0xf\n\t"
        "v_fmac_f32_dpp %3, %8, %21 row_ror:14 row_mask:0xf bank_mask:0xf\n\t"
        "v_fmac_f32_dpp %7, %9, %21 row_ror:14 row_mask:0xf bank_mask:0xf\n\t"
        "v_fmac_f32_dpp %0, %8, %22 row_ror:3 row_mask:0xf bank_mask:0xf\n\t"
        "v_fmac_f32_dpp %4, %9, %22 row_ror:3 row_mask:0xf bank_mask:0xf\n\t"
        "v_fmac_f32_dpp %1, %8, %23 row_ror:7 row_mask:0xf bank_mask:0xf\n\t"
        "v_fmac_f32_dpp %5, %9, %23 row_ror:7 row_mask:0xf bank_mask:0xf\n\t"
        "v_fmac_f32_dpp %2, %8, %24 row_ror:11 row_mask:0xf bank_mask:0xf\n\t"
        "v_fmac_f32_dpp %6, %9, %24 row_ror:11 row_mask:0xf bank_mask:0xf\n\t"
        "v_fmac_f32_dpp %3, %8, %25 row_ror:15 row_mask:0xf bank_mask:0xf\n\t"
        "v_fmac_f32_dpp %7, %9, %25 row_ror:15 row_mask:0xf bank_mask:0xf"
        : "+v"(a0A), "=&v"(a1A), "=&v"(a2A), "=&v"(a3A),
          "+v"(a0B), "=&v"(a1B), "=&v"(a2B), "=&v"(a3B)
        : "v"(hA), "v"(hB),
          "v"(Wp[0]), "v"(Wp[4]), "v"(Wp[8]), "v"(Wp[12]),
          "v"(Wp[1]), "v"(Wp[5]), "v"(Wp[9]), "v"(Wp[13]),
          "v"(Wp[2]), "v"(Wp[6]), "v"(Wp[10]), "v"(Wp[14]),
          "v"(Wp[3]), "v"(Wp[7]), "v"(Wp[11]), "v"(Wp[15]));
    float zA = (a0A + a1A) + (a2A + a3A);
    float zB = (a0B + a1B) + (a2B + a3B);

    float czA = __cosf(zA);
    float czB = __cosf(zB);
    // combined inclusive prefix product (DPP Hillis-Steele), A/B interleaved:
    // invalid lanes keep dst (BC=0) = multiplicative identity; the other
    // chain's instruction covers each DPP hazard slot.
    if constexpr (BASE == 0x110) {
        asm volatile(
            "s_nop 1\n\t"
            "v_mul_f32_dpp %0, %0, %0 row_shr:1 row_mask:0xf bank_mask:0xf\n\t"
            "v_mul_f32_dpp %1, %1, %1 row_shr:1 row_mask:0xf bank_mask:0xf\n\t"
            "v_mul_f32_dpp %0, %0, %0 row_shr:2 row_mask:0xf bank_mask:0xf\n\t"
            "v_mul_f32_dpp %1, %1, %1 row_shr:2 row_mask:0xf bank_mask:0xf\n\t"
            "v_mul_f32_dpp %0, %0, %0 row_shr:4 row_mask:0xf bank_mask:0xf\n\t"
            "v_mul_f32_dpp %1, %1, %1 row_shr:4 row_mask:0xf bank_mask:0xf\n\t"
            "v_mul_f32_dpp %0, %0, %0 row_shr:8 row_mask:0xf bank_mask:0xf\n\t"
            "v_mul_f32_dpp %1, %1, %1 row_shr:8 row_mask:0xf bank_mask:0xf"
            : "+v"(czA), "+v"(czB));
    } else {
        asm volatile(
            "s_nop 1\n\t"
            "v_mul_f32_dpp %0, %0, %0 row_shl:1 row_mask:0xf bank_mask:0xf\n\t"
            "v_mul_f32_dpp %1, %1, %1 row_shl:1 row_mask:0xf bank_mask:0xf\n\t"
            "v_mul_f32_dpp %0, %0, %0 row_shl:2 row_mask:0xf bank_mask:0xf\n\t"
            "v_mul_f32_dpp %1, %1, %1 row_shl:2 row_mask:0xf bank_mask:0xf\n\t"
            "v_mul_f32_dpp %0, %0, %0 row_shl:4 row_mask:0xf bank_mask:0xf\n\t"
            "v_mul_f32_dpp %1, %1, %1 row_shl:4 row_mask:0xf bank_mask:0xf\n\t"
            "v_mul_f32_dpp %0, %0, %0 row_shl:8 row_mask:0xf bank_mask:0xf\n\t"
            "v_mul_f32_dpp %1, %1, %1 row_shl:8 row_mask:0xf bank_mask:0xf"
            : "+v"(czA), "+v"(czB));
    }

    // gates: s = fmaf(ksc, 1/(1+2^(cz*kexp)), koff)
    //   g!=2: kexp=-log2e  -> sigmoid(cz);  g==2: kexp=-2log2e, ksc=2, koff=-1 -> tanh(cz)
    float eA = __builtin_amdgcn_exp2f(czA * kexp);
    float eB = __builtin_amdgcn_exp2f(czB * kexp);
    float rrA = __builtin_amdgcn_rcpf(1.f + eA);
    float rrB = __builtin_amdgcn_rcpf(1.f + eB);
    float sA = fmaf(ksc, rrA, koff);
    float sB = fmaf(ksc, rrB, koff);

    float fvA, ivA, gvA, ovA, fvB, ivB, gvB, ovB;
    gex(sA, m0, m1, a_f, a_i, a_g, a_o, fvA, ivA, gvA, ovA);
    gex(sB, m0, m1, a_f, a_i, a_g, a_o, fvB, ivB, gvB, ovB);

    cA = fmaf(fvA, cA, ivA * gvA);
    cB = fmaf(fvB, cB, ivB * gvB);
    // tanh(c) = 2/(1+2^(-2c*log2e)) - 1
    float e2A = __builtin_amdgcn_exp2f(cA * -2.885390082f);
    float e2B = __builtin_amdgcn_exp2f(cB * -2.885390082f);
    float tcA = fmaf(2.f, __builtin_amdgcn_rcpf(1.f + e2A), -1.f);
    float tcB = fmaf(2.f, __builtin_amdgcn_rcpf(1.f + e2B), -1.f);
    hA = ovA * tcA;
    hB = ovB * tcB;

    if ((t & 3) == g) { hsA = hA; hsB = hB; }
    if ((t & 3) == 3) {
        out[(size_t)(t - 3 + g) * (BATCH * NQ) + (size_t)bA * NQ + n] = hsA;
        out[(size_t)(t - 3 + g) * (BATCH * NQ) + (size_t)bB * NQ + n] = hsB;
    }
}

// ---------------- fused per-wave main (2 batches / wave) ----------------
// MFMA A-row m <-> (batch = bA + (m>>3), t_local = m&7); 32 tiles of 8 steps.
// wfh/wfl[kt*4+nb][lane]: W fragments in LDS, built once (one barrier).
template <int BASE, typename InT>
__device__ __forceinline__ void fused_main(
    const InT* __restrict__ x, const InT* __restrict__ W,
    const InT* __restrict__ bv, const InT* __restrict__ th,
    float* __restrict__ out, int bA, int w, int lane,
    const float (&Wp)[16], float (*zt)[ZROW],
    bf16x8 (*wfh)[64], bf16x8 (*wfl)[64])
{
    const int m = lane & 15, quad = lane >> 4;
    const int g = quad, n = m;
    const int bB = bA + 1;
    const bool m0 = (g & 1) != 0, m1 = (g & 2) != 0;
    const float kexp = (g == 2) ? -2.885390082f : -1.442695041f;
    const float ksc  = (g == 2) ? 2.f : 1.f;
    const float koff = (g == 2) ? -1.f : 0.f;
    const int a_f = n << 2, a_i = (16 + n) << 2, a_g = (32 + n) << 2, a_o = (48 + n) << 2;

    // ---- cooperative W-fragment build: wave w handles k-tile kt = w ----
    if constexpr (sizeof(InT) == 2) {
#pragma unroll
        for (int nb = 0; nb < 4; ++nb)
            wfh[w * 4 + nb][lane] = *(const bf16x8*)((const unsigned short*)W +
                                    (size_t)(nb * 16 + m) * DTOT + w * 32 + quad * 8);
    } else {
#pragma unroll
        for (int nb = 0; nb < 4; ++nb) {
            const float* p = (const float*)W + (size_t)(nb * 16 + m) * DTOT + w * 32 + quad * 8;
            bf16x8 ah, al;
#pragma unroll
            for (int j = 0; j < 8; ++j) {
                float wv = p[j];
                unsigned short hh = f2bf(wv);
                ah[j] = (short)hh;
                al[j] = (short)f2bf(wv - bf2f(hh));
            }
            wfh[w * 4 + nb][lane] = ah;
            wfl[w * 4 + nb][lane] = al;
        }
    }
    const float bias = ldval(bv + lane) + ldval(th + lane);
    __syncthreads();            // the ONLY barrier; wf* read-only afterwards

    // A-row m -> x row (t = tl*8 + (m&7), batch = bA + (m>>3))
    const InT* xbase = x + ((size_t)(m & 7) * BATCH + (size_t)(bA + (m >> 3))) * DIN + quad * 8;

    f32x4 rx[8]; bf16x8 rbx[4];
    auto LOAD = [&](int tl) {
        const InT* p = xbase + (size_t)tl * ((size_t)8 * BATCH * DIN);
#pragma unroll
        for (int kt = 0; kt < 4; ++kt) {
            if constexpr (sizeof(InT) == 2) {
                rbx[kt] = *(const bf16x8*)(p + kt * 32);
            } else {
                rx[2 * kt]     = *(const f32x4*)((const float*)p + kt * 32);
                rx[2 * kt + 1] = *(const f32x4*)((const float*)p + kt * 32 + 4);
            }
        }
    };
    auto PRODUCE = [&]() {
        f32x4 acc[4] = {};
#pragma unroll
        for (int kt = 0; kt < 4; ++kt) {
            if constexpr (sizeof(InT) == 2) {
#pragma unroll
                for (int nb = 0; nb < 4; ++nb)
                    acc[nb] = __builtin_amdgcn_mfma_f32_16x16x32_bf16(rbx[kt], wfh[kt * 4 + nb][lane], acc[nb], 0, 0, 0);
            } else {
                bf16x8 ah, al;
#pragma unroll
                for (int j = 0; j < 8; ++j) {
                    float xv = rx[2 * kt + (j >> 2)][j & 3];
                    unsigned short hh = f2bf(xv);
                    ah[j] = (short)hh;
                    al[j] = (short)f2bf(xv - bf2f(hh));
                }
#pragma unroll
                for (int nb = 0; nb < 4; ++nb)
                    acc[nb] = __builtin_amdgcn_mfma_f32_16x16x32_bf16(ah, wfh[kt * 4 + nb][lane], acc[nb], 0, 0, 0);
#pragma unroll
                for (int nb = 0; nb < 4; ++nb)
                    acc[nb] = __builtin_amdgcn_mfma_f32_16x16x32_bf16(al, wfh[kt * 4 + nb][lane], acc[nb], 0, 0, 0);
#pragma unroll
                for (int nb = 0; nb < 4; ++nb)
                    acc[nb] = __builtin_amdgcn_mfma_f32_16x16x32_bf16(ah, wfl[kt * 4 + nb][lane], acc[nb], 0, 0, 0);
            }
        }
        // z[row = quad*4+r][col = nb*16+m]; rows 0..7 = batch A t0..7, 8..15 = batch B
#pragma unroll
        for (int nb = 0; nb < 4; ++nb)
#pragma unroll
            for (int r = 0; r < 4; ++r)
                zt[quad * 4 + r][nb * 16 + m] = acc[nb][r];
    };

    float hA = 0.f, cA = 0.f, hsA = 0.f;
    float hB = 0.f, cB = 0.f, hsB = 0.f;

    LOAD(0);
    PRODUCE();
    LOAD(1);

#pragma unroll 1
    for (int tl = 0; tl < NTILE; ++tl) {
        const int t0 = tl * 8;
        float zrA[8], zrB[8];
#pragma unroll
        for (int j = 0; j < 8; ++j) zrA[j] = zt[j][lane] + bias;       // drain before overwrite
#pragma unroll
        for (int j = 0; j < 8; ++j) zrB[j] = zt[8 + j][lane] + bias;
        if (tl < NTILE - 1) PRODUCE();
        if (tl < NTILE - 2) LOAD(tl + 2);
#pragma unroll
        for (int j = 0; j < 8; ++j)
            qstep2<BASE>(t0 + j, g, n, zrA[j], zrB[j], Wp,
                         hA, cA, hsA, bA, hB, cB, hsB, bB,
                         m0, m1, kexp, ksc, koff, a_f, a_i, a_g, a_o, out);
    }

    if (g == 0) {
        out[(size_t)T_STEPS * BATCH * NQ + (size_t)bA * NQ + n] = hA;                      // hx
        out[(size_t)T_STEPS * BATCH * NQ + (size_t)BATCH * NQ + (size_t)bA * NQ + n] = cA; // cx
        out[(size_t)T_STEPS * BATCH * NQ + (size_t)bB * NQ + n] = hB;
        out[(size_t)T_STEPS * BATCH * NQ + (size_t)BATCH * NQ + (size_t)bB * NQ + n] = cB;
    }
}

__global__ __launch_bounds__(256, 1) void qlstm_fused(
    const void* __restrict__ x_, const void* __restrict__ W_,
    const void* __restrict__ b_, const void* __restrict__ th_,
    float* __restrict__ out)
{
    __shared__ float  zw[4][16][ZROW];      // 16.5 KiB: per-wave z tiles
    __shared__ bf16x8 wfh[16][64];          // 16 KiB: W hi fragments (shared)
    __shared__ bf16x8 wfl[16][64];          // 16 KiB: W lo fragments (fp32 path)

    const int lane = threadIdx.x & 63;
    const int w    = threadIdx.x >> 6;
    const int bA   = (blockIdx.x * 4 + w) * 2;
    const int n    = lane & 15;

    const int isbf = __builtin_amdgcn_readfirstlane(detect_bf16((const unsigned int*)x_, lane));

    // runtime probe of DPP row_ror direction (wave-uniform)
    int pr  = __builtin_amdgcn_update_dpp(0, lane, 0x121, 0xF, 0xF, false);
    int p0r = __shfl(pr, 0, 64);
    const int d = (p0r == 1) ? 1 : 15;

    float Wp[16];
    if (isbf) {
        const unsigned short* W = (const unsigned short*)W_;
#pragma unroll
        for (int k = 0; k < 16; ++k)
            Wp[k] = bf2f(W[(size_t)lane * DTOT + DIN + ((n + k * d) & 15)]);
    } else {
        const float* W = (const float*)W_;
#pragma unroll
        for (int k = 0; k < 16; ++k)
            Wp[k] = W[(size_t)lane * DTOT + DIN + ((n + k * d) & 15)];
    }

    // runtime probe of DPP row_shr direction (wave-uniform) for the prefix product
    int probe = __builtin_amdgcn_update_dpp(999, lane, 0x111, 0xF, 0xF, false);
    int p2 = __shfl(probe, 2, 64);

    if (isbf) {
        if (p2 == 1) fused_main<0x110, unsigned short>((const unsigned short*)x_, (const unsigned short*)W_,
                                                       (const unsigned short*)b_, (const unsigned short*)th_,
                                                       out, bA, w, lane, Wp, zw[w], wfh, wfl);
        else         fused_main<0x100, unsigned short>((const unsigned short*)x_, (const unsigned short*)W_,
                                                       (const unsigned short*)b_, (const unsigned short*)th_,
                                                       out, bA, w, lane, Wp, zw[w], wfh, wfl);
    } else {
        if (p2 == 1) fused_main<0x110, float>((const float*)x_, (const float*)W_,
                                              (const float*)b_, (const float*)th_,
                                              out, bA, w, lane, Wp, zw[w], wfh, wfl);
        else         fused_main<0x100, float>((const float*)x_, (const float*)W_,
                                              (const float*)b_, (const float*)th_,
                                              out, bA, w, lane, Wp, zw[w], wfh, wfl);
    }
}

extern "C" void kernel_launch(void* const* d_in, const int* in_sizes, int n_in,
                              void* d_out, int out_size, void* d_ws, size_t ws_size,
                              hipStream_t stream) {
    const void* x  = d_in[0];
    const void* W  = d_in[1];
    const void* bv = d_in[2];
    const void* th = d_in[3];
    (void)d_ws; (void)ws_size;
    qlstm_fused<<<BATCH / 8, 256, 0, stream>>>(x, W, bv, th, (float*)d_out);
}